// Round 4
// baseline (1843.109 us; speedup 1.0000x reference)
//
#include <hip/hip_runtime.h>

using short8 = __attribute__((ext_vector_type(8))) short;
using f32x4  = __attribute__((ext_vector_type(4))) float;

__device__ __forceinline__ unsigned short f2bf(float x){
    unsigned u = __float_as_uint(x);
    unsigned r = (u + 0x7FFFu + ((u>>16)&1u)) >> 16;
    return (unsigned short)r;
}
__device__ __forceinline__ float bf2f(unsigned short h){
    return __uint_as_float(((unsigned)h)<<16);
}
__device__ __forceinline__ float sigf(float x){ return 1.0f/(1.0f+__expf(-x)); }
// XOR swizzle: flip byte bits 4-6 with bits 7-9 (breaks 64B/pixel bank alignment)
__device__ __forceinline__ int swz(int b){ return b ^ (((b>>7)&7)<<4); }

struct MP {
    const float *x;
    const float *W1,*U1,*b1,*g1,*be1,*m1,*v1;
    const float *W2,*U2,*b2,*g2,*be2,*m2,*v2;
    const float *W3,*U3,*b3,*g3,*be3,*m3,*v3;
    const float *Wd1,*bd1,*Wd2,*bd2;
    unsigned short *hs, *pooled;
    float *cst, *xz, *bp, *partial;
    short8 *U1b,*W1b,*U2b,*W2b,*U3b,*W3b;
    float *out;
    unsigned *bar;
};

// device-scope grid barrier (all 256 blocks co-resident: grid == #CUs, LDS 40KB)
__device__ __forceinline__ void gsync(unsigned* bar, unsigned target){
    __syncthreads();
    if (threadIdx.x == 0) {
        __threadfence();
        __hip_atomic_fetch_add(bar, 1u, __ATOMIC_ACQ_REL, __HIP_MEMORY_SCOPE_AGENT);
        while (__hip_atomic_load(bar, __ATOMIC_ACQUIRE, __HIP_MEMORY_SCOPE_AGENT) < target)
            __builtin_amdgcn_s_sleep(2);
        __threadfence();
    }
    __syncthreads();
}

// ---------------- weight/bias transform into MFMA fragment layout ----------------
__device__ void xform_dev(int i, const MP& p)
{
    if (i >= 49536) return;
    if (i >= 49152) {                      // permuted biases, 3 layers x 128
        int j = i - 49152, layer = j >> 7, np = j & 127;
        int oc = ((np>>4)&3)*32 + (np>>6)*16 + (np&15);
        const float* bs = layer==0 ? p.b1 : (layer==1 ? p.b2 : p.b3);
        p.bp[j] = bs[oc];
        return;
    }
    const float* src; short8* dst; int base, kmax;
    if      (i < 12800){ src=p.U1; dst=p.U1b; base=0;     kmax=800; }
    else if (i < 14336){ src=p.W1; dst=p.W1b; base=12800; kmax=75;  }
    else if (i < 27136){ src=p.U2; dst=p.U2b; base=14336; kmax=800; }
    else if (i < 39936){ src=p.W2; dst=p.W2b; base=27136; kmax=800; }
    else if (i < 44544){ src=p.U3; dst=p.U3b; base=39936; kmax=288; }
    else               { src=p.W3; dst=p.W3b; base=44544; kmax=288; }
    int j = i - base;
    int lane = j & 63, nt = (j >> 6) & 7, tap = j >> 9;
    int np = nt*16 + (lane & 15);
    int oc = ((np>>4)&3)*32 + (np>>6)*16 + (np&15);
    int g = lane >> 4;
    short8 pk;
    #pragma unroll
    for (int e = 0; e < 8; ++e) {
        int k = tap*32 + g*8 + e;
        unsigned short v = (k < kmax) ? f2bf(src[(long)k*128 + oc]) : (unsigned short)0;
        pk[e] = (short)v;
    }
    dst[j] = pk;
}

// ---------------- MFMA conv phase (+ optional fused LSTM gates + BN/pool) ----------------
template<int K, int TH, bool FUSE, bool HASX>
__device__ void conv_phase(char* smem,
               const unsigned short* __restrict__ src, long src_nstride,
               const short8* __restrict__ Ub,
               const float* __restrict__ xsrc, long x_nstride,
               const short8* __restrict__ Wb,
               const float* __restrict__ xz, long xz_nstride,
               const float* __restrict__ bp,
               unsigned short* __restrict__ outh, long outh_nstride,
               float* __restrict__ xzout,
               float* __restrict__ cst,
               unsigned short* __restrict__ pool_out,
               const float* __restrict__ gg, const float* __restrict__ bb,
               const float* __restrict__ mm, const float* __restrict__ vv,
               int H, int W, int n, int y0, int x0, int t, int T, int first)
{
    static_assert(!HASX || TH == 8, "HASX path assumes 128-pixel tile");
    constexpr int PAD = K/2;
    constexpr int PH  = TH + K - 1;
    constexpr int PW  = 16 + K - 1;
    constexpr int MT2 = TH/2;
    constexpr int NTAP = K*K;
    constexpr int MPX = TH*16;

    unsigned short* patch_s = (unsigned short*)smem;
    unsigned short* xpk_s   = (unsigned short*)(smem + PH*PW*64);

    const int tid = threadIdx.x;
    const int xt  = x0 >> 4;
    const int lane = tid & 63;
    const int wid  = tid >> 6;
    const int mh = wid >> 1, nh = wid & 1;
    const int l15 = lane & 15, g4 = lane >> 4;

    const bool do_h = !(FUSE && first);

    // ---- stage recurrent/conv input patch (bf16, swizzled) ----
    if (do_h) {
        const unsigned short* s = src + (long)n * src_nstride;
        #pragma unroll 1
        for (int c = tid; c < PH*PW*4; c += 256) {
            int pix = c >> 2, gq = c & 3;
            int pr = pix / PW, pc = pix % PW;
            int gy = y0 - PAD + pr, gx = x0 - PAD + pc;
            short8 v = {0,0,0,0,0,0,0,0};
            if ((unsigned)gy < (unsigned)H && (unsigned)gx < (unsigned)W)
                v = *(const short8*)(s + ((long)gy*W + gx)*32 + gq*8);
            *(short8*)((char*)patch_s + swz(pix*64 + gq*16)) = v;
        }
    }
    // ---- stage x im2col (L1 only): (pixel,tap) scatter; pad k-region pre-zeroed ----
    if constexpr (HASX) {
        const float* xs = xsrc + (long)n * x_nstride;
        #pragma unroll 1
        for (int c = tid; c < MPX*25; c += 256) {
            int p = c & (MPX-1), tap = c >> 7;
            int dy = tap/5, dx = tap - dy*5;
            int gy = y0 + (p>>4) - PAD + dy;
            int gx = x0 + (p&15) - PAD + dx;
            float v0=0.f, v1=0.f, v2=0.f;
            if ((unsigned)gy < (unsigned)H && (unsigned)gx < (unsigned)W) {
                const float* b = xs + ((long)gy*W + gx)*3;
                v0 = b[0]; v1 = b[1]; v2 = b[2];
            }
            int o = p*192 + tap*6;
            *(unsigned short*)((char*)xpk_s + swz(o))   = f2bf(v0);
            *(unsigned short*)((char*)xpk_s + swz(o+2)) = f2bf(v1);
            *(unsigned short*)((char*)xpk_s + swz(o+4)) = f2bf(v2);
        }
    }
    __syncthreads();

    // ---- init accumulators ----
    f32x4 acc[MT2][4];
    if (FUSE && !HASX) {
        const float* zp = xz + (long)n * xz_nstride;
        #pragma unroll
        for (int mt = 0; mt < MT2; ++mt) {
            int row = y0 + mh*MT2 + mt;
            #pragma unroll
            for (int ntl = 0; ntl < 4; ++ntl) {
                int np = (nh*4+ntl)*16 + l15;
                acc[mt][ntl] = *(const f32x4*)&zp[(((long)row*(W>>4)) + xt)*2048 + np*16 + g4*4];
            }
        }
    } else {
        #pragma unroll
        for (int ntl = 0; ntl < 4; ++ntl) {
            float bv = bp[(nh*4+ntl)*16 + l15];
            #pragma unroll
            for (int mt = 0; mt < MT2; ++mt)
                acc[mt][ntl] = (f32x4){bv,bv,bv,bv};
        }
    }

    // ---- x-conv K-chunks (L1) ----
    if constexpr (HASX) {
        #pragma unroll 1
        for (int c = 0; c < 3; ++c) {
            const short8* wp = Wb + ((long)c*8 + nh*4)*64 + lane;
            short8 bf0 = wp[0], bf1 = wp[64], bf2 = wp[128], bf3 = wp[192];
            #pragma unroll
            for (int mt = 0; mt < MT2; ++mt) {
                short8 af = *(const short8*)((const char*)xpk_s +
                    swz(((mh*MT2+mt)*16 + l15)*192 + c*64 + g4*16));
                acc[mt][0] = __builtin_amdgcn_mfma_f32_16x16x32_bf16(af, bf0, acc[mt][0], 0,0,0);
                acc[mt][1] = __builtin_amdgcn_mfma_f32_16x16x32_bf16(af, bf1, acc[mt][1], 0,0,0);
                acc[mt][2] = __builtin_amdgcn_mfma_f32_16x16x32_bf16(af, bf2, acc[mt][2], 0,0,0);
                acc[mt][3] = __builtin_amdgcn_mfma_f32_16x16x32_bf16(af, bf3, acc[mt][3], 0,0,0);
            }
        }
    }

    // ---- recurrent-conv tap loop, B double-buffered 2 taps ahead ----
    if (do_h) {
        const short8* ub = Ub + (long)nh*4*64 + lane;       // tap stride = 512 short8
        short8 bA0 = ub[0], bA1 = ub[64], bA2 = ub[128], bA3 = ub[192];
        short8 bB0 = bA0, bB1 = bA1, bB2 = bA2, bB3 = bA3;
        { const short8* u = ub + 512; bB0=u[0]; bB1=u[64]; bB2=u[128]; bB3=u[192]; }
        #pragma unroll 1
        for (int tp = 0; tp < NTAP; tp += 2) {
            {
                int dy = tp / K, dx = tp % K;
                #pragma unroll
                for (int mt = 0; mt < MT2; ++mt) {
                    short8 af = *(const short8*)((const char*)patch_s +
                        swz(((mh*MT2 + mt + dy)*PW + l15 + dx)*64 + g4*16));
                    acc[mt][0] = __builtin_amdgcn_mfma_f32_16x16x32_bf16(af, bA0, acc[mt][0], 0,0,0);
                    acc[mt][1] = __builtin_amdgcn_mfma_f32_16x16x32_bf16(af, bA1, acc[mt][1], 0,0,0);
                    acc[mt][2] = __builtin_amdgcn_mfma_f32_16x16x32_bf16(af, bA2, acc[mt][2], 0,0,0);
                    acc[mt][3] = __builtin_amdgcn_mfma_f32_16x16x32_bf16(af, bA3, acc[mt][3], 0,0,0);
                }
                if (tp + 2 < NTAP) { const short8* u = ub + (long)(tp+2)*512; bA0=u[0];bA1=u[64];bA2=u[128];bA3=u[192]; }
            }
            if (tp + 1 < NTAP) {
                int dy = (tp+1) / K, dx = (tp+1) % K;
                #pragma unroll
                for (int mt = 0; mt < MT2; ++mt) {
                    short8 af = *(const short8*)((const char*)patch_s +
                        swz(((mh*MT2 + mt + dy)*PW + l15 + dx)*64 + g4*16));
                    acc[mt][0] = __builtin_amdgcn_mfma_f32_16x16x32_bf16(af, bB0, acc[mt][0], 0,0,0);
                    acc[mt][1] = __builtin_amdgcn_mfma_f32_16x16x32_bf16(af, bB1, acc[mt][1], 0,0,0);
                    acc[mt][2] = __builtin_amdgcn_mfma_f32_16x16x32_bf16(af, bB2, acc[mt][2], 0,0,0);
                    acc[mt][3] = __builtin_amdgcn_mfma_f32_16x16x32_bf16(af, bB3, acc[mt][3], 0,0,0);
                }
                if (tp + 3 < NTAP) { const short8* u = ub + (long)(tp+3)*512; bB0=u[0];bB1=u[64];bB2=u[128];bB3=u[192]; }
            }
        }
    }

    // ---- epilogue ----
    if constexpr (FUSE) {
        const int f = nh*16 + l15;
        const float sc = gg[f] * rsqrtf(vv[f] + 1e-3f);
        const float sh = bb[f] - mm[f]*sc;
        float hv[MT2][4];
        #pragma unroll
        for (int mt = 0; mt < MT2; ++mt) {
            int row = y0 + mh*MT2 + mt;
            #pragma unroll
            for (int j = 0; j < 4; ++j) {
                int col = x0 + g4*4 + j;
                float zi = acc[mt][0][j];
                float zf = acc[mt][1][j];
                float zg = acc[mt][2][j];
                float zo = acc[mt][3][j];
                long cix = (((long)n*H + row)*W + col)*32 + f;
                float cold = first ? 0.0f : cst[cix];
                float cn = sigf(zf)*cold + sigf(zi)*fmaxf(zg, 0.0f);
                cst[cix] = cn;
                float h = sigf(zo)*fmaxf(cn, 0.0f);
                hv[mt][j] = h;
                outh[(long)n*outh_nstride + ((long)row*W + col)*32 + f] = f2bf(h);
            }
        }
        #pragma unroll
        for (int mp = 0; mp < MT2/2; ++mp) {
            int orow = (y0>>1) + mh*(MT2/2) + mp;
            #pragma unroll
            for (int jp = 0; jp < 2; ++jp) {
                int ocol = (x0>>1) + g4*2 + jp;
                float mx = fmaxf(fmaxf(hv[2*mp][2*jp],   hv[2*mp][2*jp+1]),
                                 fmaxf(hv[2*mp+1][2*jp], hv[2*mp+1][2*jp+1]));
                pool_out[(((long)(n*T + t)*(H>>1) + orow)*(W>>1) + ocol)*32 + f] = f2bf(mx*sc + sh);
            }
        }
    } else {
        float* zo = xzout + (long)n * (long)H * (W>>4) * 2048;
        #pragma unroll
        for (int mt = 0; mt < MT2; ++mt) {
            int row = y0 + mh*MT2 + mt;
            #pragma unroll
            for (int ntl = 0; ntl < 4; ++ntl) {
                int np = (nh*4+ntl)*16 + l15;
                *(f32x4*)&zo[(((long)row*(W>>4)) + xt)*2048 + np*16 + g4*4] = acc[mt][ntl];
            }
        }
    }
}

// ---------------- dense layer 1 phase: K-split partial GEMM ----------------
__device__ void dense1_dev(char* smem, int kc,
                           const unsigned short* __restrict__ flat,
                           const float* __restrict__ Wd1, float* __restrict__ partial)
{
    float* xs = (float*)smem;            // 256*8 floats
    const int k0 = kc*256;
    const int t = threadIdx.x;
    {
        int r = t >> 5, kb = (t & 31)*8;
        short8 v = *(const short8*)(flat + (long)r*20480 + k0 + kb);
        #pragma unroll
        for (int e = 0; e < 8; ++e) xs[(kb+e)*8 + r] = bf2f((unsigned short)v[e]);
    }
    __syncthreads();
    const int c = t & 63, seg = t >> 6;
    f32x4 accA = {0,0,0,0}, accB = {0,0,0,0};
    #pragma unroll 4
    for (int kk = seg*64; kk < seg*64 + 64; ++kk) {
        float w = Wd1[(long)(k0+kk)*64 + c];
        f32x4 xa = *(const f32x4*)&xs[kk*8];
        f32x4 xb = *(const f32x4*)&xs[kk*8 + 4];
        #pragma unroll
        for (int j = 0; j < 4; ++j) { accA[j] = fmaf(xa[j], w, accA[j]); accB[j] = fmaf(xb[j], w, accB[j]); }
    }
    __syncthreads();
    #pragma unroll
    for (int j = 0; j < 4; ++j) {
        xs[(seg*8 + j)*64 + c]     = accA[j];
        xs[(seg*8 + 4 + j)*64 + c] = accB[j];
    }
    __syncthreads();
    #pragma unroll
    for (int o = t; o < 512; o += 256) {
        int r = o >> 6, cc = o & 63;
        partial[(long)kc*512 + o] = (xs[(0*8+r)*64+cc] + xs[(1*8+r)*64+cc])
                                  + (xs[(2*8+r)*64+cc] + xs[(3*8+r)*64+cc]);
    }
}

// ---------------- dense tail phase (block 0, 256 threads) ----------------
__device__ void dense_tail_dev(char* smem, const float* __restrict__ partial,
                               const float* __restrict__ bd1, const float* __restrict__ Wd2,
                               const float* __restrict__ bd2, float* __restrict__ outp)
{
    float* d1  = (float*)smem;       // 512
    float* l2s = d1 + 512;           // 80
    const int tid = threadIdx.x;
    #pragma unroll
    for (int rr = 0; rr < 2; ++rr) {
        int idx = rr*256 + tid;
        int c = idx & 63;
        float s = bd1[c];
        #pragma unroll 4
        for (int kc = 0; kc < 80; ++kc) s += partial[kc*512 + idx];
        float mx = s;
        for (int o = 32; o > 0; o >>= 1) mx = fmaxf(mx, __shfl_xor(mx, o, 64));
        float e = __expf(s - mx);
        float sm = e;
        for (int o = 32; o > 0; o >>= 1) sm += __shfl_xor(sm, o, 64);
        d1[idx] = e / sm;
    }
    __syncthreads();
    if (tid < 80) {
        int r = tid / 10, o = tid % 10;
        float l = bd2[o];
        #pragma unroll 8
        for (int cc = 0; cc < 64; ++cc) l = fmaf(d1[r*64 + cc], Wd2[cc*10 + o], l);
        l2s[tid] = l;
    }
    __syncthreads();
    if (tid < 8) {
        float mx2 = l2s[tid*10];
        #pragma unroll
        for (int j = 1; j < 10; ++j) mx2 = fmaxf(mx2, l2s[tid*10 + j]);
        float ev[10], s2 = 0.f;
        #pragma unroll
        for (int j = 0; j < 10; ++j) { ev[j] = __expf(l2s[tid*10 + j] - mx2); s2 += ev[j]; }
        #pragma unroll
        for (int j = 0; j < 10; ++j) outp[tid*10 + j] = ev[j] / s2;
    }
}

// ---------------- the persistent mega-kernel ----------------
__global__ __launch_bounds__(256, 1)
void mega(MP p)
{
    __shared__ __align__(16) char smem[40960];
    const int bid = blockIdx.x, tid = threadIdx.x;
    unsigned ep = 0;

    // phase 0: weight/bias transform
    xform_dev(bid*256 + tid, p);
    gsync(p.bar, (++ep)*256);

    // ----- Layer 1: 64x64, k5, x-conv fused; 256 blocks (tile 8x16) -----
    {
        const long HW = 4096;
        int n = bid >> 5, rem = bid & 31;
        int y0 = (rem >> 2) * 8, x0 = (rem & 3) * 16;
        // zero the im2col pad region once (k slots 75..95 stay zero all steps)
        short8 z8 = {0,0,0,0,0,0,0,0};
        #pragma unroll 1
        for (int c = tid; c < 128*96/8; c += 256)
            ((short8*)(smem + 15360))[c] = z8;
        __syncthreads();
        for (int t = 0; t < 10; ++t) {
            conv_phase<5,8,true,true>(smem,
                p.hs + (long)(t>0?t-1:0)*HW*32, (long)10*HW*32,
                p.U1b,
                p.x + (long)t*HW*3, (long)10*HW*3,
                p.W1b,
                nullptr, 0,
                p.bp,
                p.hs + (long)t*HW*32, (long)10*HW*32,
                nullptr, p.cst, p.pooled,
                p.g1, p.be1, p.m1, p.v1,
                64, 64, n, y0, x0, t, 10, t==0 ? 1 : 0);
            gsync(p.bar, (++ep)*256);
        }
    }
    // ----- Layer 2 xz precompute: 640 units grid-strided -----
    {
        const long HW = 1024;
        #pragma unroll 1
        for (int u = bid; u < 640; u += 256) {
            int n = u >> 3, rem = u & 7;
            int y0 = (rem >> 1)*8, x0 = (rem & 1)*16;
            conv_phase<5,8,false,false>(smem,
                p.pooled, HW*32, p.W2b,
                nullptr, 0, nullptr,
                nullptr, 0,
                p.bp + 128,
                nullptr, 0,
                p.xz, nullptr, nullptr,
                nullptr, nullptr, nullptr, nullptr,
                32, 32, n, y0, x0, 0, 1, 0);
            __syncthreads();
        }
        gsync(p.bar, (++ep)*256);
    }
    // ----- Layer 2 steps: 128 active blocks (tile 4x16) -----
    {
        const long HW = 1024;
        int n = bid >> 4, rem = bid & 15;
        int y0 = (rem >> 1)*4, x0 = (rem & 1)*16;
        for (int t = 0; t < 10; ++t) {
            if (bid < 128)
                conv_phase<5,4,true,false>(smem,
                    p.hs + (long)(t>0?t-1:0)*HW*32, (long)10*HW*32,
                    p.U2b,
                    nullptr, 0, nullptr,
                    p.xz + (long)t*HW*128, (long)10*HW*128,
                    nullptr,
                    p.hs + (long)t*HW*32, (long)10*HW*32,
                    nullptr, p.cst, p.pooled,
                    p.g2, p.be2, p.m2, p.v2,
                    32, 32, n, y0, x0, t, 10, t==0 ? 1 : 0);
            gsync(p.bar, (++ep)*256);
        }
    }
    // ----- Layer 3 xz precompute: 320 units grid-strided -----
    {
        const long HW = 256;
        #pragma unroll 1
        for (int u = bid; u < 320; u += 256) {
            int n = u >> 2, rem = u & 3;
            conv_phase<3,4,false,false>(smem,
                p.pooled, HW*32, p.W3b,
                nullptr, 0, nullptr,
                nullptr, 0,
                p.bp + 256,
                nullptr, 0,
                p.xz, nullptr, nullptr,
                nullptr, nullptr, nullptr, nullptr,
                16, 16, n, rem*4, 0, 0, 1, 0);
            __syncthreads();
        }
        gsync(p.bar, (++ep)*256);
    }
    // ----- Layer 3 steps: 32 active blocks (tile 4x16) -----
    {
        const long HW = 256;
        int n = bid >> 2, rem = bid & 3;
        for (int t = 0; t < 10; ++t) {
            if (bid < 32)
                conv_phase<3,4,true,false>(smem,
                    p.hs + (long)(t>0?t-1:0)*HW*32, (long)10*HW*32,
                    p.U3b,
                    nullptr, 0, nullptr,
                    p.xz + (long)t*HW*128, (long)10*HW*128,
                    nullptr,
                    p.hs + (long)t*HW*32, (long)10*HW*32,
                    nullptr, p.cst, p.pooled,
                    p.g3, p.be3, p.m3, p.v3,
                    16, 16, n, rem*4, 0, t, 10, t==0 ? 1 : 0);
            gsync(p.bar, (++ep)*256);
        }
    }
    // ----- dense head -----
    if (bid < 80) dense1_dev(smem, bid, p.pooled, p.Wd1, p.partial);
    gsync(p.bar, (++ep)*256);
    if (bid == 0) dense_tail_dev(smem, p.partial, p.bd1, p.Wd2, p.bd2, p.out);
}

extern "C" void kernel_launch(void* const* d_in, const int* in_sizes, int n_in,
                              void* d_out, int out_size, void* d_ws, size_t ws_size,
                              hipStream_t stream)
{
    char* ws = (char*)d_ws;
    MP p;
    p.x   = (const float*)d_in[0];
    p.W1  = (const float*)d_in[1];  p.U1  = (const float*)d_in[2];  p.b1 = (const float*)d_in[3];
    p.g1  = (const float*)d_in[4];  p.be1 = (const float*)d_in[5];  p.m1 = (const float*)d_in[6];  p.v1 = (const float*)d_in[7];
    p.W2  = (const float*)d_in[8];  p.U2  = (const float*)d_in[9];  p.b2 = (const float*)d_in[10];
    p.g2  = (const float*)d_in[11]; p.be2 = (const float*)d_in[12]; p.m2 = (const float*)d_in[13]; p.v2 = (const float*)d_in[14];
    p.W3  = (const float*)d_in[15]; p.U3  = (const float*)d_in[16]; p.b3 = (const float*)d_in[17];
    p.g3  = (const float*)d_in[18]; p.be3 = (const float*)d_in[19]; p.m3 = (const float*)d_in[20]; p.v3 = (const float*)d_in[21];
    p.Wd1 = (const float*)d_in[22]; p.bd1 = (const float*)d_in[23];
    p.Wd2 = (const float*)d_in[24]; p.bd2 = (const float*)d_in[25];

    p.hs      = (unsigned short*)(ws);                 // 20,971,520 B (bf16)
    p.cst     = (float*)(ws + 20971520);               //  4,194,304 B
    p.pooled  = (unsigned short*)(ws + 25165824);      //  5,242,880 B
    p.xz      = (float*)(ws + 30408704);               // 41,943,040 B
    p.U1b     = (short8*)(ws + 72351744);
    p.W1b     = (short8*)(ws + 72556544);
    p.U2b     = (short8*)(ws + 72581120);
    p.W2b     = (short8*)(ws + 72785920);
    p.U3b     = (short8*)(ws + 72990720);
    p.W3b     = (short8*)(ws + 73064448);
    p.bp      = (float*)(ws + 73138176);
    p.partial = (float*)(ws + 73139712);               // 163,840 B
    p.bar     = (unsigned*)(ws + 73303552);
    p.out     = (float*)d_out;

    hipMemsetAsync(p.bar, 0, 64, stream);              // deterministic barrier state per call
    mega<<<256, 256, 0, stream>>>(p);
}

// Round 5
// 610.284 us; speedup vs baseline: 3.0201x; 3.0201x over previous
//
#include <hip/hip_runtime.h>

using short8 = __attribute__((ext_vector_type(8))) short;
using f32x4  = __attribute__((ext_vector_type(4))) float;

__device__ __forceinline__ unsigned short f2bf(float x){
    unsigned u = __float_as_uint(x);
    unsigned r = (u + 0x7FFFu + ((u>>16)&1u)) >> 16;
    return (unsigned short)r;
}
__device__ __forceinline__ float bf2f(unsigned short h){
    return __uint_as_float(((unsigned)h)<<16);
}
__device__ __forceinline__ float sigf(float x){ return 1.0f/(1.0f+__expf(-x)); }
// XOR swizzle: flip byte bits 4-6 with bits 7-9 (breaks 64B/pixel bank alignment)
__device__ __forceinline__ int swz(int b){ return b ^ (((b>>7)&7)<<4); }

struct MP {
    const float *x;
    const float *W1,*U1,*b1,*g1,*be1,*m1,*v1;
    const float *W2,*U2,*b2,*g2,*be2,*m2,*v2;
    const float *W3,*U3,*b3,*g3,*be3,*m3,*v3;
    const float *Wd1,*bd1,*Wd2,*bd2;
    unsigned short *hs, *pooled;
    float *cst, *xz, *bp, *partial;
    short8 *U1b,*W1b,*U2b,*W2b,*U3b,*W3b;
    float *out;
    unsigned *bar;
};

// Barrier: arrival add has RELEASE (one L2 writeback); poll is RELAXED agent
// loads (bypass stale L2, invalidate NOTHING); single ACQUIRE fence on exit.
// All 256 blocks co-resident (grid == #CUs, 1 block/CU guaranteed).
__device__ __forceinline__ void gbar(unsigned* ctr, unsigned target){
    __syncthreads();
    if (threadIdx.x == 0) {
        __hip_atomic_fetch_add(ctr, 1u, __ATOMIC_RELEASE, __HIP_MEMORY_SCOPE_AGENT);
        while (__hip_atomic_load(ctr, __ATOMIC_RELAXED, __HIP_MEMORY_SCOPE_AGENT) < target)
            __builtin_amdgcn_s_sleep(8);
        __builtin_amdgcn_fence(__ATOMIC_ACQUIRE, "agent");
    }
    __syncthreads();
}

// ---------------- weight/bias transform into MFMA fragment layout ----------------
__device__ void xform_dev(int i, const MP& p)
{
    if (i >= 49536) return;
    if (i >= 49152) {                      // permuted biases, 3 layers x 128
        int j = i - 49152, layer = j >> 7, np = j & 127;
        int oc = ((np>>4)&3)*32 + (np>>6)*16 + (np&15);
        const float* bs = layer==0 ? p.b1 : (layer==1 ? p.b2 : p.b3);
        p.bp[j] = bs[oc];
        return;
    }
    const float* src; short8* dst; int base, kmax;
    if      (i < 12800){ src=p.U1; dst=p.U1b; base=0;     kmax=800; }
    else if (i < 14336){ src=p.W1; dst=p.W1b; base=12800; kmax=75;  }
    else if (i < 27136){ src=p.U2; dst=p.U2b; base=14336; kmax=800; }
    else if (i < 39936){ src=p.W2; dst=p.W2b; base=27136; kmax=800; }
    else if (i < 44544){ src=p.U3; dst=p.U3b; base=39936; kmax=288; }
    else               { src=p.W3; dst=p.W3b; base=44544; kmax=288; }
    int j = i - base;
    int lane = j & 63, nt = (j >> 6) & 7, tap = j >> 9;
    int np = nt*16 + (lane & 15);
    int oc = ((np>>4)&3)*32 + (np>>6)*16 + (np&15);
    int g = lane >> 4;
    short8 pk;
    #pragma unroll
    for (int e = 0; e < 8; ++e) {
        int k = tap*32 + g*8 + e;
        unsigned short v = (k < kmax) ? f2bf(src[(long)k*128 + oc]) : (unsigned short)0;
        pk[e] = (short)v;
    }
    dst[j] = pk;
}

// ---------------- MFMA conv phase (+ optional fused LSTM gates + BN/pool) ----------------
template<int K, int TH, bool FUSE, bool HASX>
__device__ void conv_phase(char* smem,
               const unsigned short* __restrict__ src, long src_nstride,
               const short8* __restrict__ Ub,
               const float* __restrict__ xsrc, long x_nstride,
               const short8* __restrict__ Wb,
               const float* __restrict__ xz, long xz_nstride,
               const float* __restrict__ bp,
               unsigned short* __restrict__ outh, long outh_nstride,
               float* __restrict__ xzout,
               float* __restrict__ cst,
               unsigned short* __restrict__ pool_out,
               const float* __restrict__ gg, const float* __restrict__ bb,
               const float* __restrict__ mm, const float* __restrict__ vv,
               int H, int W, int n, int y0, int x0, int t, int T, int first)
{
    static_assert(!HASX || TH == 8, "HASX path assumes 128-pixel tile");
    constexpr int PAD = K/2;
    constexpr int PH  = TH + K - 1;
    constexpr int PW  = 16 + K - 1;
    constexpr int MT2 = TH/2;
    constexpr int NTAP = K*K;
    constexpr int MPX = TH*16;

    unsigned short* patch_s = (unsigned short*)smem;
    unsigned short* xpk_s   = (unsigned short*)(smem + PH*PW*64);

    const int tid = threadIdx.x;
    const int xt  = x0 >> 4;
    const int lane = tid & 63;
    const int wid  = tid >> 6;
    const int mh = wid >> 1, nh = wid & 1;
    const int l15 = lane & 15, g4 = lane >> 4;

    const bool do_h = !(FUSE && first);

    // ---- stage recurrent/conv input patch (bf16, swizzled) ----
    if (do_h) {
        const unsigned short* s = src + (long)n * src_nstride;
        #pragma unroll 1
        for (int c = tid; c < PH*PW*4; c += 256) {
            int pix = c >> 2, gq = c & 3;
            int pr = pix / PW, pc = pix % PW;
            int gy = y0 - PAD + pr, gx = x0 - PAD + pc;
            short8 v = {0,0,0,0,0,0,0,0};
            if ((unsigned)gy < (unsigned)H && (unsigned)gx < (unsigned)W)
                v = *(const short8*)(s + ((long)gy*W + gx)*32 + gq*8);
            *(short8*)((char*)patch_s + swz(pix*64 + gq*16)) = v;
        }
    }
    // ---- stage x im2col (L1 only): (pixel,tap) scatter; pad k-region pre-zeroed ----
    if constexpr (HASX) {
        const float* xs = xsrc + (long)n * x_nstride;
        #pragma unroll 1
        for (int c = tid; c < MPX*25; c += 256) {
            int p = c & (MPX-1), tap = c >> 7;
            int dy = tap/5, dx = tap - dy*5;
            int gy = y0 + (p>>4) - PAD + dy;
            int gx = x0 + (p&15) - PAD + dx;
            float v0=0.f, v1=0.f, v2=0.f;
            if ((unsigned)gy < (unsigned)H && (unsigned)gx < (unsigned)W) {
                const float* b = xs + ((long)gy*W + gx)*3;
                v0 = b[0]; v1 = b[1]; v2 = b[2];
            }
            int o = p*192 + tap*6;
            *(unsigned short*)((char*)xpk_s + swz(o))   = f2bf(v0);
            *(unsigned short*)((char*)xpk_s + swz(o+2)) = f2bf(v1);
            *(unsigned short*)((char*)xpk_s + swz(o+4)) = f2bf(v2);
        }
    }
    __syncthreads();

    // ---- init accumulators ----
    f32x4 acc[MT2][4];
    if (FUSE && !HASX) {
        const float* zp = xz + (long)n * xz_nstride;
        #pragma unroll
        for (int mt = 0; mt < MT2; ++mt) {
            int row = y0 + mh*MT2 + mt;
            #pragma unroll
            for (int ntl = 0; ntl < 4; ++ntl) {
                int np = (nh*4+ntl)*16 + l15;
                acc[mt][ntl] = *(const f32x4*)&zp[(((long)row*(W>>4)) + xt)*2048 + np*16 + g4*4];
            }
        }
    } else {
        #pragma unroll
        for (int ntl = 0; ntl < 4; ++ntl) {
            float bv = bp[(nh*4+ntl)*16 + l15];
            #pragma unroll
            for (int mt = 0; mt < MT2; ++mt)
                acc[mt][ntl] = (f32x4){bv,bv,bv,bv};
        }
    }

    // ---- x-conv K-chunks (L1) ----
    if constexpr (HASX) {
        #pragma unroll 1
        for (int c = 0; c < 3; ++c) {
            const short8* wp = Wb + ((long)c*8 + nh*4)*64 + lane;
            short8 bf0 = wp[0], bf1 = wp[64], bf2 = wp[128], bf3 = wp[192];
            #pragma unroll
            for (int mt = 0; mt < MT2; ++mt) {
                short8 af = *(const short8*)((const char*)xpk_s +
                    swz(((mh*MT2+mt)*16 + l15)*192 + c*64 + g4*16));
                acc[mt][0] = __builtin_amdgcn_mfma_f32_16x16x32_bf16(af, bf0, acc[mt][0], 0,0,0);
                acc[mt][1] = __builtin_amdgcn_mfma_f32_16x16x32_bf16(af, bf1, acc[mt][1], 0,0,0);
                acc[mt][2] = __builtin_amdgcn_mfma_f32_16x16x32_bf16(af, bf2, acc[mt][2], 0,0,0);
                acc[mt][3] = __builtin_amdgcn_mfma_f32_16x16x32_bf16(af, bf3, acc[mt][3], 0,0,0);
            }
        }
    }

    // ---- recurrent-conv tap loop, B double-buffered 2 taps ahead ----
    if (do_h) {
        const short8* ub = Ub + (long)nh*4*64 + lane;       // tap stride = 512 short8
        short8 bA0 = ub[0], bA1 = ub[64], bA2 = ub[128], bA3 = ub[192];
        short8 bB0 = bA0, bB1 = bA1, bB2 = bA2, bB3 = bA3;
        { const short8* u = ub + 512; bB0=u[0]; bB1=u[64]; bB2=u[128]; bB3=u[192]; }
        #pragma unroll 1
        for (int tp = 0; tp < NTAP; tp += 2) {
            {
                int dy = tp / K, dx = tp % K;
                #pragma unroll
                for (int mt = 0; mt < MT2; ++mt) {
                    short8 af = *(const short8*)((const char*)patch_s +
                        swz(((mh*MT2 + mt + dy)*PW + l15 + dx)*64 + g4*16));
                    acc[mt][0] = __builtin_amdgcn_mfma_f32_16x16x32_bf16(af, bA0, acc[mt][0], 0,0,0);
                    acc[mt][1] = __builtin_amdgcn_mfma_f32_16x16x32_bf16(af, bA1, acc[mt][1], 0,0,0);
                    acc[mt][2] = __builtin_amdgcn_mfma_f32_16x16x32_bf16(af, bA2, acc[mt][2], 0,0,0);
                    acc[mt][3] = __builtin_amdgcn_mfma_f32_16x16x32_bf16(af, bA3, acc[mt][3], 0,0,0);
                }
                if (tp + 2 < NTAP) { const short8* u = ub + (long)(tp+2)*512; bA0=u[0];bA1=u[64];bA2=u[128];bA3=u[192]; }
            }
            if (tp + 1 < NTAP) {
                int dy = (tp+1) / K, dx = (tp+1) % K;
                #pragma unroll
                for (int mt = 0; mt < MT2; ++mt) {
                    short8 af = *(const short8*)((const char*)patch_s +
                        swz(((mh*MT2 + mt + dy)*PW + l15 + dx)*64 + g4*16));
                    acc[mt][0] = __builtin_amdgcn_mfma_f32_16x16x32_bf16(af, bB0, acc[mt][0], 0,0,0);
                    acc[mt][1] = __builtin_amdgcn_mfma_f32_16x16x32_bf16(af, bB1, acc[mt][1], 0,0,0);
                    acc[mt][2] = __builtin_amdgcn_mfma_f32_16x16x32_bf16(af, bB2, acc[mt][2], 0,0,0);
                    acc[mt][3] = __builtin_amdgcn_mfma_f32_16x16x32_bf16(af, bB3, acc[mt][3], 0,0,0);
                }
                if (tp + 3 < NTAP) { const short8* u = ub + (long)(tp+3)*512; bB0=u[0];bB1=u[64];bB2=u[128];bB3=u[192]; }
            }
        }
    }

    // ---- epilogue ----
    if constexpr (FUSE) {
        const int f = nh*16 + l15;
        const float sc = gg[f] * rsqrtf(vv[f] + 1e-3f);
        const float sh = bb[f] - mm[f]*sc;
        float hv[MT2][4];
        #pragma unroll
        for (int mt = 0; mt < MT2; ++mt) {
            int row = y0 + mh*MT2 + mt;
            #pragma unroll
            for (int j = 0; j < 4; ++j) {
                int col = x0 + g4*4 + j;
                float zi = acc[mt][0][j];
                float zf = acc[mt][1][j];
                float zg = acc[mt][2][j];
                float zo = acc[mt][3][j];
                long cix = (((long)n*H + row)*W + col)*32 + f;
                float cold = first ? 0.0f : cst[cix];
                float cn = sigf(zf)*cold + sigf(zi)*fmaxf(zg, 0.0f);
                cst[cix] = cn;
                float h = sigf(zo)*fmaxf(cn, 0.0f);
                hv[mt][j] = h;
                outh[(long)n*outh_nstride + ((long)row*W + col)*32 + f] = f2bf(h);
            }
        }
        #pragma unroll
        for (int mp = 0; mp < MT2/2; ++mp) {
            int orow = (y0>>1) + mh*(MT2/2) + mp;
            #pragma unroll
            for (int jp = 0; jp < 2; ++jp) {
                int ocol = (x0>>1) + g4*2 + jp;
                float mx = fmaxf(fmaxf(hv[2*mp][2*jp],   hv[2*mp][2*jp+1]),
                                 fmaxf(hv[2*mp+1][2*jp], hv[2*mp+1][2*jp+1]));
                pool_out[(((long)(n*T + t)*(H>>1) + orow)*(W>>1) + ocol)*32 + f] = f2bf(mx*sc + sh);
            }
        }
    } else {
        float* zo = xzout + (long)n * (long)H * (W>>4) * 2048;
        #pragma unroll
        for (int mt = 0; mt < MT2; ++mt) {
            int row = y0 + mh*MT2 + mt;
            #pragma unroll
            for (int ntl = 0; ntl < 4; ++ntl) {
                int np = (nh*4+ntl)*16 + l15;
                *(f32x4*)&zo[(((long)row*(W>>4)) + xt)*2048 + np*16 + g4*4] = acc[mt][ntl];
            }
        }
    }
}

// ---------------- dense layer 1 phase: K-split partial GEMM ----------------
__device__ void dense1_dev(char* smem, int kc,
                           const unsigned short* __restrict__ flat,
                           const float* __restrict__ Wd1, float* __restrict__ partial)
{
    float* xs = (float*)smem;            // 256*8 floats
    const int k0 = kc*256;
    const int t = threadIdx.x;
    {
        int r = t >> 5, kb = (t & 31)*8;
        short8 v = *(const short8*)(flat + (long)r*20480 + k0 + kb);
        #pragma unroll
        for (int e = 0; e < 8; ++e) xs[(kb+e)*8 + r] = bf2f((unsigned short)v[e]);
    }
    __syncthreads();
    const int c = t & 63, seg = t >> 6;
    f32x4 accA = {0,0,0,0}, accB = {0,0,0,0};
    #pragma unroll 4
    for (int kk = seg*64; kk < seg*64 + 64; ++kk) {
        float w = Wd1[(long)(k0+kk)*64 + c];
        f32x4 xa = *(const f32x4*)&xs[kk*8];
        f32x4 xb = *(const f32x4*)&xs[kk*8 + 4];
        #pragma unroll
        for (int j = 0; j < 4; ++j) { accA[j] = fmaf(xa[j], w, accA[j]); accB[j] = fmaf(xb[j], w, accB[j]); }
    }
    __syncthreads();
    #pragma unroll
    for (int j = 0; j < 4; ++j) {
        xs[(seg*8 + j)*64 + c]     = accA[j];
        xs[(seg*8 + 4 + j)*64 + c] = accB[j];
    }
    __syncthreads();
    #pragma unroll
    for (int o = t; o < 512; o += 256) {
        int r = o >> 6, cc = o & 63;
        partial[(long)kc*512 + o] = (xs[(0*8+r)*64+cc] + xs[(1*8+r)*64+cc])
                                  + (xs[(2*8+r)*64+cc] + xs[(3*8+r)*64+cc]);
    }
}

// ---------------- dense tail phase (block 0, 256 threads) ----------------
__device__ void dense_tail_dev(char* smem, const float* __restrict__ partial,
                               const float* __restrict__ bd1, const float* __restrict__ Wd2,
                               const float* __restrict__ bd2, float* __restrict__ outp)
{
    float* d1  = (float*)smem;       // 512
    float* l2s = d1 + 512;           // 80
    const int tid = threadIdx.x;
    #pragma unroll
    for (int rr = 0; rr < 2; ++rr) {
        int idx = rr*256 + tid;
        int c = idx & 63;
        float s = bd1[c];
        #pragma unroll 4
        for (int kc = 0; kc < 80; ++kc) s += partial[kc*512 + idx];
        float mx = s;
        for (int o = 32; o > 0; o >>= 1) mx = fmaxf(mx, __shfl_xor(mx, o, 64));
        float e = __expf(s - mx);
        float sm = e;
        for (int o = 32; o > 0; o >>= 1) sm += __shfl_xor(sm, o, 64);
        d1[idx] = e / sm;
    }
    __syncthreads();
    if (tid < 80) {
        int r = tid / 10, o = tid % 10;
        float l = bd2[o];
        #pragma unroll 8
        for (int cc = 0; cc < 64; ++cc) l = fmaf(d1[r*64 + cc], Wd2[cc*10 + o], l);
        l2s[tid] = l;
    }
    __syncthreads();
    if (tid < 8) {
        float mx2 = l2s[tid*10];
        #pragma unroll
        for (int j = 1; j < 10; ++j) mx2 = fmaxf(mx2, l2s[tid*10 + j]);
        float ev[10], s2 = 0.f;
        #pragma unroll
        for (int j = 0; j < 10; ++j) { ev[j] = __expf(l2s[tid*10 + j] - mx2); s2 += ev[j]; }
        #pragma unroll
        for (int j = 0; j < 10; ++j) outp[tid*10 + j] = ev[j] / s2;
    }
}

// ---------------- the persistent mega-kernel ----------------
// Barrier counters (128B apart): ctr[0]=global, ctr[32*(1+n)]=L1 group n,
// ctr[32*(9+n)]=L2 group n, ctr[32*(17+n)]=L3 group n.
__global__ __launch_bounds__(256, 1)
void mega(MP p)
{
    __shared__ __align__(16) char smem[40960];
    const int bid = blockIdx.x, tid = threadIdx.x;
    unsigned* C = p.bar;
    unsigned g_ep = 0;

    // phase 0: weight/bias transform
    xform_dev(bid*256 + tid, p);
    gbar(C, (++g_ep)*256);

    // ----- Layer 1: 64x64, k5, x-conv fused; 256 blocks (tile 8x16); groups of 32 per n -----
    {
        const long HW = 4096;
        int n = bid >> 5, rem = bid & 31;
        int y0 = (rem >> 2) * 8, x0 = (rem & 3) * 16;
        unsigned* c1 = C + 32*(1 + n);
        // zero the im2col pad region once (k slots 75..95 stay zero all steps)
        short8 z8 = {0,0,0,0,0,0,0,0};
        #pragma unroll 1
        for (int c = tid; c < 128*96/8; c += 256)
            ((short8*)(smem + 15360))[c] = z8;
        __syncthreads();
        for (int t = 0; t < 10; ++t) {
            conv_phase<5,8,true,true>(smem,
                p.hs + (long)(t>0?t-1:0)*HW*32, (long)10*HW*32,
                p.U1b,
                p.x + (long)t*HW*3, (long)10*HW*3,
                p.W1b,
                nullptr, 0,
                p.bp,
                p.hs + (long)t*HW*32, (long)10*HW*32,
                nullptr, p.cst, p.pooled,
                p.g1, p.be1, p.m1, p.v1,
                64, 64, n, y0, x0, t, 10, t==0 ? 1 : 0);
            if (t < 9) gbar(c1, (unsigned)(t+1)*32);
        }
        gbar(C, (++g_ep)*256);
    }
    // ----- Layer 2 xz precompute: 640 units grid-strided -----
    {
        const long HW = 1024;
        #pragma unroll 1
        for (int u = bid; u < 640; u += 256) {
            int n = u >> 3, rem = u & 7;
            int y0 = (rem >> 1)*8, x0 = (rem & 1)*16;
            conv_phase<5,8,false,false>(smem,
                p.pooled, HW*32, p.W2b,
                nullptr, 0, nullptr,
                nullptr, 0,
                p.bp + 128,
                nullptr, 0,
                p.xz, nullptr, nullptr,
                nullptr, nullptr, nullptr, nullptr,
                32, 32, n, y0, x0, 0, 1, 0);
            __syncthreads();
        }
        gbar(C, (++g_ep)*256);
    }
    // ----- Layer 2 steps: 128 active blocks (tile 4x16); groups of 16 per n -----
    {
        const long HW = 1024;
        int n = bid >> 4, rem = bid & 15;
        int y0 = (rem >> 1)*4, x0 = (rem & 1)*16;
        unsigned* c2 = C + 32*(9 + (n & 7));
        for (int t = 0; t < 10; ++t) {
            if (bid < 128) {
                conv_phase<5,4,true,false>(smem,
                    p.hs + (long)(t>0?t-1:0)*HW*32, (long)10*HW*32,
                    p.U2b,
                    nullptr, 0, nullptr,
                    p.xz + (long)t*HW*128, (long)10*HW*128,
                    nullptr,
                    p.hs + (long)t*HW*32, (long)10*HW*32,
                    nullptr, p.cst, p.pooled,
                    p.g2, p.be2, p.m2, p.v2,
                    32, 32, n, y0, x0, t, 10, t==0 ? 1 : 0);
                if (t < 9) gbar(c2, (unsigned)(t+1)*16);
            }
        }
        gbar(C, (++g_ep)*256);
    }
    // ----- Layer 3 xz precompute: 320 units grid-strided -----
    {
        const long HW = 256;
        #pragma unroll 1
        for (int u = bid; u < 320; u += 256) {
            int n = u >> 2, rem = u & 3;
            conv_phase<3,4,false,false>(smem,
                p.pooled, HW*32, p.W3b,
                nullptr, 0, nullptr,
                nullptr, 0,
                p.bp + 256,
                nullptr, 0,
                p.xz, nullptr, nullptr,
                nullptr, nullptr, nullptr, nullptr,
                16, 16, n, rem*4, 0, 0, 1, 0);
            __syncthreads();
        }
        gbar(C, (++g_ep)*256);
    }
    // ----- Layer 3 steps: 32 active blocks (tile 4x16); groups of 4 per n -----
    {
        const long HW = 256;
        int n = bid >> 2, rem = bid & 3;
        unsigned* c3 = C + 32*(17 + (n & 7));
        for (int t = 0; t < 10; ++t) {
            if (bid < 32) {
                conv_phase<3,4,true,false>(smem,
                    p.hs + (long)(t>0?t-1:0)*HW*32, (long)10*HW*32,
                    p.U3b,
                    nullptr, 0, nullptr,
                    p.xz + (long)t*HW*128, (long)10*HW*128,
                    nullptr,
                    p.hs + (long)t*HW*32, (long)10*HW*32,
                    nullptr, p.cst, p.pooled,
                    p.g3, p.be3, p.m3, p.v3,
                    16, 16, n, rem*4, 0, t, 10, t==0 ? 1 : 0);
                if (t < 9) gbar(c3, (unsigned)(t+1)*4);
            }
        }
        gbar(C, (++g_ep)*256);
    }
    // ----- dense head -----
    if (bid < 80) dense1_dev(smem, bid, p.pooled, p.Wd1, p.partial);
    gbar(C, (++g_ep)*256);
    if (bid == 0) dense_tail_dev(smem, p.partial, p.bd1, p.Wd2, p.bd2, p.out);
}

extern "C" void kernel_launch(void* const* d_in, const int* in_sizes, int n_in,
                              void* d_out, int out_size, void* d_ws, size_t ws_size,
                              hipStream_t stream)
{
    char* ws = (char*)d_ws;
    MP p;
    p.x   = (const float*)d_in[0];
    p.W1  = (const float*)d_in[1];  p.U1  = (const float*)d_in[2];  p.b1 = (const float*)d_in[3];
    p.g1  = (const float*)d_in[4];  p.be1 = (const float*)d_in[5];  p.m1 = (const float*)d_in[6];  p.v1 = (const float*)d_in[7];
    p.W2  = (const float*)d_in[8];  p.U2  = (const float*)d_in[9];  p.b2 = (const float*)d_in[10];
    p.g2  = (const float*)d_in[11]; p.be2 = (const float*)d_in[12]; p.m2 = (const float*)d_in[13]; p.v2 = (const float*)d_in[14];
    p.W3  = (const float*)d_in[15]; p.U3  = (const float*)d_in[16]; p.b3 = (const float*)d_in[17];
    p.g3  = (const float*)d_in[18]; p.be3 = (const float*)d_in[19]; p.m3 = (const float*)d_in[20]; p.v3 = (const float*)d_in[21];
    p.Wd1 = (const float*)d_in[22]; p.bd1 = (const float*)d_in[23];
    p.Wd2 = (const float*)d_in[24]; p.bd2 = (const float*)d_in[25];

    p.hs      = (unsigned short*)(ws);                 // 20,971,520 B (bf16)
    p.cst     = (float*)(ws + 20971520);               //  4,194,304 B
    p.pooled  = (unsigned short*)(ws + 25165824);      //  5,242,880 B
    p.xz      = (float*)(ws + 30408704);               // 41,943,040 B
    p.U1b     = (short8*)(ws + 72351744);
    p.W1b     = (short8*)(ws + 72556544);
    p.U2b     = (short8*)(ws + 72581120);
    p.W2b     = (short8*)(ws + 72785920);
    p.U3b     = (short8*)(ws + 72990720);
    p.W3b     = (short8*)(ws + 73064448);
    p.bp      = (float*)(ws + 73138176);
    p.partial = (float*)(ws + 73139712);               // 163,840 B
    p.bar     = (unsigned*)(ws + 73303552);            // 25 counters, 128B apart
    p.out     = (float*)d_out;

    hipMemsetAsync(p.bar, 0, 4096, stream);            // deterministic barrier state per call
    mega<<<256, 256, 0, stream>>>(p);
}

// Round 6
// 237.786 us; speedup vs baseline: 7.7511x; 2.5665x over previous
//
#include <hip/hip_runtime.h>

using short8 = __attribute__((ext_vector_type(8))) short;
using f32x4  = __attribute__((ext_vector_type(4))) float;

__device__ __forceinline__ unsigned short f2bf(float x){
    unsigned u = __float_as_uint(x);
    unsigned r = (u + 0x7FFFu + ((u>>16)&1u)) >> 16;
    return (unsigned short)r;
}
__device__ __forceinline__ float bf2f(unsigned short h){
    return __uint_as_float(((unsigned)h)<<16);
}
__device__ __forceinline__ float sigf(float x){ return 1.0f/(1.0f+__expf(-x)); }
// XOR swizzle: flip byte bits 4-6 with bits 7-9 (stays inside each 1KB block)
__device__ __forceinline__ int swz(int b){ return b ^ (((b>>7)&7)<<4); }

struct SP {
    const float *x;
    const float *g1,*be1,*m1,*v1;
    const float *g2,*be2,*m2,*v2;
    const float *g3,*be3,*m3,*v3;
    unsigned short *hs1,*hs2,*hs3;
    unsigned short *pl1,*pl2,*pl3;   // pooled outputs (bf16, [n][t][y][x][f])
    float *cst1,*cst2,*cst3;
    const short8 *U1b,*W1b,*U2b,*W2b,*U3b,*W3b;
    const float *bp;
};

// ---------------- weight/bias transform into MFMA fragment layout ----------------
// frag tensor: [tap][nt 0..7][lane 0..63] of short8; gate-permuted output channels.
__global__ __launch_bounds__(256)
void xform_all(const float* __restrict__ U1, const float* __restrict__ W1,
               const float* __restrict__ U2, const float* __restrict__ W2,
               const float* __restrict__ U3, const float* __restrict__ W3,
               const float* __restrict__ b1, const float* __restrict__ b2, const float* __restrict__ b3,
               short8* __restrict__ U1b, short8* __restrict__ W1b,
               short8* __restrict__ U2b, short8* __restrict__ W2b,
               short8* __restrict__ U3b, short8* __restrict__ W3b,
               float* __restrict__ bp)
{
    int i = blockIdx.x*256 + threadIdx.x;
    if (i >= 49536) return;
    if (i >= 49152) {                      // permuted biases, 3 layers x 128
        int j = i - 49152, layer = j >> 7, np = j & 127;
        int oc = ((np>>4)&3)*32 + (np>>6)*16 + (np&15);
        const float* bs = layer==0 ? b1 : (layer==1 ? b2 : b3);
        bp[j] = bs[oc];
        return;
    }
    const float* src; short8* dst; int base, kmax;
    if      (i < 12800){ src=U1; dst=U1b; base=0;     kmax=800; }
    else if (i < 14336){ src=W1; dst=W1b; base=12800; kmax=75;  }
    else if (i < 27136){ src=U2; dst=U2b; base=14336; kmax=800; }
    else if (i < 39936){ src=W2; dst=W2b; base=27136; kmax=800; }
    else if (i < 44544){ src=U3; dst=U3b; base=39936; kmax=288; }
    else               { src=W3; dst=W3b; base=44544; kmax=288; }
    int j = i - base;
    int lane = j & 63, nt = (j >> 6) & 7, tap = j >> 9;
    int np = nt*16 + (lane & 15);
    int oc = ((np>>4)&3)*32 + (np>>6)*16 + (np&15);
    int g = lane >> 4;
    short8 pk;
    #pragma unroll
    for (int e = 0; e < 8; ++e) {
        int k = tap*32 + g*8 + e;
        unsigned short v = (k < kmax) ? f2bf(src[(long)k*128 + oc]) : (unsigned short)0;
        pk[e] = (short)v;
    }
    dst[j] = pk;
}

// ---------------- shared epilogue: LSTM gates + cell + h-write + pool/BN ----------------
template<int MT2>
__device__ __forceinline__ void lstm_epilogue(
    f32x4 (&acc)[MT2][4], unsigned short* hs, float* cst, unsigned short* plout,
    const float* gg, const float* bb, const float* mm, const float* vv,
    int H, int W, int n, int y0, int x0, int t, int mh, int nh, int l15, int g4, int first)
{
    const int f = nh*16 + l15;
    const float sc = gg[f] * rsqrtf(vv[f] + 1e-3f);
    const float sh = bb[f] - mm[f]*sc;
    unsigned short* outh = hs + ((long)n*10 + t)*(long)H*W*32;
    float hv[MT2][4];
    #pragma unroll
    for (int mt = 0; mt < MT2; ++mt) {
        int row = y0 + mh*MT2 + mt;
        #pragma unroll
        for (int j = 0; j < 4; ++j) {
            int col = x0 + g4*4 + j;
            float zi = acc[mt][0][j];
            float zf = acc[mt][1][j];
            float zg = acc[mt][2][j];
            float zo = acc[mt][3][j];
            long cix = (((long)n*H + row)*W + col)*32 + f;
            float cold = first ? 0.0f : cst[cix];
            float cn = sigf(zf)*cold + sigf(zi)*fmaxf(zg, 0.0f);
            cst[cix] = cn;
            float h = sigf(zo)*fmaxf(cn, 0.0f);
            hv[mt][j] = h;
            outh[((long)row*W + col)*32 + f] = f2bf(h);
        }
    }
    #pragma unroll
    for (int mp = 0; mp < MT2/2; ++mp) {
        int orow = (y0>>1) + mh*(MT2/2) + mp;
        #pragma unroll
        for (int jp = 0; jp < 2; ++jp) {
            int ocol = (x0>>1) + g4*2 + jp;
            float mx = fmaxf(fmaxf(hv[2*mp][2*jp],   hv[2*mp][2*jp+1]),
                             fmaxf(hv[2*mp+1][2*jp], hv[2*mp+1][2*jp+1]));
            plout[(((long)(n*10 + t)*(H>>1) + orow)*(W>>1) + ocol)*32 + f] = f2bf(mx*sc + sh);
        }
    }
}

// ---------------- L1 step: im2col x-conv (Cin=3) + recurrent conv, fused gates ----------------
__device__ void l1_step(char* smem, const SP& p, int n, int y0, int x0, int t)
{
    constexpr int K = 5, TH = 8, PAD = 2, PH = 12, PW = 20, MT2 = 4, NTAP = 25, MPX = 128;
    const int H = 64, W = 64;
    unsigned short* patch_s = (unsigned short*)smem;                    // 15360 B
    unsigned short* xpk_s   = (unsigned short*)(smem + PH*PW*64);       // 24576 B

    const int tid = threadIdx.x;
    const int lane = tid & 63, wid = tid >> 6;
    const int mh = wid >> 1, nh = wid & 1;
    const int l15 = lane & 15, g4 = lane >> 4;
    const int first = (t == 0);

    // zero-fill im2col buffer (pad k-slots must be 0)
    short8 z8 = {0,0,0,0,0,0,0,0};
    #pragma unroll 1
    for (int c = tid; c < MPX*96/8; c += 256)
        ((short8*)xpk_s)[c] = z8;

    // stage h patch (t>0)
    if (!first) {
        const unsigned short* s = p.hs1 + ((long)n*10 + (t-1))*(long)H*W*32;
        #pragma unroll 1
        for (int c = tid; c < PH*PW*4; c += 256) {
            int pix = c >> 2, gq = c & 3;
            int pr = pix / PW, pc = pix % PW;
            int gy = y0 - PAD + pr, gx = x0 - PAD + pc;
            short8 v = z8;
            if ((unsigned)gy < (unsigned)H && (unsigned)gx < (unsigned)W)
                v = *(const short8*)(s + ((long)gy*W + gx)*32 + gq*8);
            *(short8*)((char*)patch_s + swz(pix*64 + gq*16)) = v;
        }
    }
    __syncthreads();
    // stage x im2col: (pixel, tap) scatter
    {
        const float* xs = p.x + ((long)n*10 + t)*(long)H*W*3;
        #pragma unroll 1
        for (int c = tid; c < MPX*25; c += 256) {
            int px = c & (MPX-1), tap = c >> 7;
            int dy = tap/5, dx = tap - dy*5;
            int gy = y0 + (px>>4) - PAD + dy;
            int gx = x0 + (px&15) - PAD + dx;
            float v0=0.f, v1=0.f, v2=0.f;
            if ((unsigned)gy < (unsigned)H && (unsigned)gx < (unsigned)W) {
                const float* b = xs + ((long)gy*W + gx)*3;
                v0 = b[0]; v1 = b[1]; v2 = b[2];
            }
            int o = px*192 + tap*6;
            *(unsigned short*)((char*)xpk_s + swz(o))   = f2bf(v0);
            *(unsigned short*)((char*)xpk_s + swz(o+2)) = f2bf(v1);
            *(unsigned short*)((char*)xpk_s + swz(o+4)) = f2bf(v2);
        }
    }
    __syncthreads();

    f32x4 acc[MT2][4];
    #pragma unroll
    for (int ntl = 0; ntl < 4; ++ntl) {
        float bv = p.bp[(nh*4+ntl)*16 + l15];
        #pragma unroll
        for (int mt = 0; mt < MT2; ++mt)
            acc[mt][ntl] = (f32x4){bv,bv,bv,bv};
    }

    // x-conv: 3 padded K-chunks
    #pragma unroll 1
    for (int c = 0; c < 3; ++c) {
        const short8* wp = p.W1b + ((long)c*8 + nh*4)*64 + lane;
        short8 bf0 = wp[0], bf1 = wp[64], bf2 = wp[128], bf3 = wp[192];
        #pragma unroll
        for (int mt = 0; mt < MT2; ++mt) {
            short8 af = *(const short8*)((const char*)xpk_s +
                swz(((mh*MT2+mt)*16 + l15)*192 + c*64 + g4*16));
            acc[mt][0] = __builtin_amdgcn_mfma_f32_16x16x32_bf16(af, bf0, acc[mt][0], 0,0,0);
            acc[mt][1] = __builtin_amdgcn_mfma_f32_16x16x32_bf16(af, bf1, acc[mt][1], 0,0,0);
            acc[mt][2] = __builtin_amdgcn_mfma_f32_16x16x32_bf16(af, bf2, acc[mt][2], 0,0,0);
            acc[mt][3] = __builtin_amdgcn_mfma_f32_16x16x32_bf16(af, bf3, acc[mt][3], 0,0,0);
        }
    }
    // recurrent conv
    if (!first) {
        const short8* ub = p.U1b + nh*4*64 + lane;
        short8 bA0 = ub[0], bA1 = ub[64], bA2 = ub[128], bA3 = ub[192];
        short8 bB0 = bA0, bB1 = bA1, bB2 = bA2, bB3 = bA3;
        { const short8* u = ub + 512; bB0=u[0]; bB1=u[64]; bB2=u[128]; bB3=u[192]; }
        #pragma unroll 1
        for (int tp = 0; tp < NTAP; tp += 2) {
            {
                int dy = tp / K, dx = tp % K;
                #pragma unroll
                for (int mt = 0; mt < MT2; ++mt) {
                    short8 af = *(const short8*)((const char*)patch_s +
                        swz(((mh*MT2 + mt + dy)*PW + l15 + dx)*64 + g4*16));
                    acc[mt][0] = __builtin_amdgcn_mfma_f32_16x16x32_bf16(af, bA0, acc[mt][0], 0,0,0);
                    acc[mt][1] = __builtin_amdgcn_mfma_f32_16x16x32_bf16(af, bA1, acc[mt][1], 0,0,0);
                    acc[mt][2] = __builtin_amdgcn_mfma_f32_16x16x32_bf16(af, bA2, acc[mt][2], 0,0,0);
                    acc[mt][3] = __builtin_amdgcn_mfma_f32_16x16x32_bf16(af, bA3, acc[mt][3], 0,0,0);
                }
                if (tp + 2 < NTAP) { const short8* u = ub + (long)(tp+2)*512; bA0=u[0];bA1=u[64];bA2=u[128];bA3=u[192]; }
            }
            if (tp + 1 < NTAP) {
                int dy = (tp+1) / K, dx = (tp+1) % K;
                #pragma unroll
                for (int mt = 0; mt < MT2; ++mt) {
                    short8 af = *(const short8*)((const char*)patch_s +
                        swz(((mh*MT2 + mt + dy)*PW + l15 + dx)*64 + g4*16));
                    acc[mt][0] = __builtin_amdgcn_mfma_f32_16x16x32_bf16(af, bB0, acc[mt][0], 0,0,0);
                    acc[mt][1] = __builtin_amdgcn_mfma_f32_16x16x32_bf16(af, bB1, acc[mt][1], 0,0,0);
                    acc[mt][2] = __builtin_amdgcn_mfma_f32_16x16x32_bf16(af, bB2, acc[mt][2], 0,0,0);
                    acc[mt][3] = __builtin_amdgcn_mfma_f32_16x16x32_bf16(af, bB3, acc[mt][3], 0,0,0);
                }
                if (tp + 3 < NTAP) { const short8* u = ub + (long)(tp+3)*512; bB0=u[0];bB1=u[64];bB2=u[128];bB3=u[192]; }
            }
        }
    }
    lstm_epilogue<MT2>(acc, p.hs1, p.cst1, p.pl1, p.g1, p.be1, p.m1, p.v1,
                       H, W, n, y0, x0, t, mh, nh, l15, g4, first);
}

// ---------------- L2/L3 step: dual conv (W ⊛ pooled_prev + U ⊛ h_prev), fused gates ----------------
template<int K, int HH>
__device__ void l23_step(char* smem, const SP& p,
    unsigned short* hs, const unsigned short* plin, unsigned short* plout, float* cst,
    const short8* Ufr, const short8* Wfr, const float* bp,
    const float* gg, const float* bb, const float* mm, const float* vv,
    int n, int y0, int x0, int t)
{
    constexpr int TH = 4, PAD = K/2, PH = TH+K-1, PW = 16+K-1, MT2 = 2, NTAP = K*K;
    const int H = HH, W = HH;
    unsigned short* patchH = (unsigned short*)smem;
    unsigned short* patchX = (unsigned short*)(smem + PH*PW*64);

    const int tid = threadIdx.x;
    const int lane = tid & 63, wid = tid >> 6;
    const int mh = wid >> 1, nh = wid & 1;
    const int l15 = lane & 15, g4 = lane >> 4;
    const int first = (t == 0);

    const unsigned short* hsrc = hs + ((long)n*10 + (t-1))*(long)H*W*32;
    const unsigned short* xsrc = plin + ((long)n*10 + t)*(long)H*W*32;
    short8 z8 = {0,0,0,0,0,0,0,0};
    #pragma unroll 1
    for (int c = tid; c < PH*PW*4; c += 256) {
        int pix = c >> 2, gq = c & 3;
        int pr = pix / PW, pc = pix % PW;
        int gy = y0 - PAD + pr, gx = x0 - PAD + pc;
        short8 vx = z8, vh = z8;
        if ((unsigned)gy < (unsigned)H && (unsigned)gx < (unsigned)W) {
            vx = *(const short8*)(xsrc + ((long)gy*W + gx)*32 + gq*8);
            if (!first) vh = *(const short8*)(hsrc + ((long)gy*W + gx)*32 + gq*8);
        }
        *(short8*)((char*)patchX + swz(pix*64 + gq*16)) = vx;
        *(short8*)((char*)patchH + swz(pix*64 + gq*16)) = vh;
    }
    __syncthreads();

    f32x4 acc[MT2][4];
    #pragma unroll
    for (int ntl = 0; ntl < 4; ++ntl) {
        float bv = bp[(nh*4+ntl)*16 + l15];
        #pragma unroll
        for (int mt = 0; mt < MT2; ++mt)
            acc[mt][ntl] = (f32x4){bv,bv,bv,bv};
    }

    auto tap_loop = [&](const unsigned short* patch, const short8* Wf) {
        const short8* ub = Wf + nh*4*64 + lane;
        short8 bA0 = ub[0], bA1 = ub[64], bA2 = ub[128], bA3 = ub[192];
        short8 bB0 = bA0, bB1 = bA1, bB2 = bA2, bB3 = bA3;
        { const short8* u = ub + 512; bB0=u[0]; bB1=u[64]; bB2=u[128]; bB3=u[192]; }
        #pragma unroll 1
        for (int tp = 0; tp < NTAP; tp += 2) {
            {
                int dy = tp / K, dx = tp % K;
                #pragma unroll
                for (int mt = 0; mt < MT2; ++mt) {
                    short8 af = *(const short8*)((const char*)patch +
                        swz(((mh*MT2 + mt + dy)*PW + l15 + dx)*64 + g4*16));
                    acc[mt][0] = __builtin_amdgcn_mfma_f32_16x16x32_bf16(af, bA0, acc[mt][0], 0,0,0);
                    acc[mt][1] = __builtin_amdgcn_mfma_f32_16x16x32_bf16(af, bA1, acc[mt][1], 0,0,0);
                    acc[mt][2] = __builtin_amdgcn_mfma_f32_16x16x32_bf16(af, bA2, acc[mt][2], 0,0,0);
                    acc[mt][3] = __builtin_amdgcn_mfma_f32_16x16x32_bf16(af, bA3, acc[mt][3], 0,0,0);
                }
                if (tp + 2 < NTAP) { const short8* u = ub + (long)(tp+2)*512; bA0=u[0];bA1=u[64];bA2=u[128];bA3=u[192]; }
            }
            if (tp + 1 < NTAP) {
                int dy = (tp+1) / K, dx = (tp+1) % K;
                #pragma unroll
                for (int mt = 0; mt < MT2; ++mt) {
                    short8 af = *(const short8*)((const char*)patch +
                        swz(((mh*MT2 + mt + dy)*PW + l15 + dx)*64 + g4*16));
                    acc[mt][0] = __builtin_amdgcn_mfma_f32_16x16x32_bf16(af, bB0, acc[mt][0], 0,0,0);
                    acc[mt][1] = __builtin_amdgcn_mfma_f32_16x16x32_bf16(af, bB1, acc[mt][1], 0,0,0);
                    acc[mt][2] = __builtin_amdgcn_mfma_f32_16x16x32_bf16(af, bB2, acc[mt][2], 0,0,0);
                    acc[mt][3] = __builtin_amdgcn_mfma_f32_16x16x32_bf16(af, bB3, acc[mt][3], 0,0,0);
                }
                if (tp + 3 < NTAP) { const short8* u = ub + (long)(tp+3)*512; bB0=u[0];bB1=u[64];bB2=u[128];bB3=u[192]; }
            }
        }
    };
    tap_loop(patchX, Wfr);                 // input conv from prev-layer pooled
    if (!first) tap_loop(patchH, Ufr);     // recurrent conv

    lstm_epilogue<MT2>(acc, hs, cst, plout, gg, bb, mm, vv,
                       H, W, n, y0, x0, t, mh, nh, l15, g4, first);
}

// ---------------- pipelined stage kernel: L1[s] || L2[s-1] || L3[s-2] ----------------
__global__ __launch_bounds__(256)
void stage_k(SP p, int s)
{
    __shared__ __align__(16) char smem[40960];
    const int bid = blockIdx.x;
    if (bid < 256) {
        int t = s;
        if (t < 10) {
            int n = bid >> 5, rem = bid & 31;
            l1_step(smem, p, n, (rem >> 2)*8, (rem & 3)*16, t);
        }
    } else if (bid < 384) {
        int t = s - 1;
        if (t >= 0 && t < 10) {
            int idx = bid - 256;
            int n = idx >> 4, rem = idx & 15;
            l23_step<5,32>(smem, p, p.hs2, p.pl1, p.pl2, p.cst2,
                           p.U2b, p.W2b, p.bp + 128,
                           p.g2, p.be2, p.m2, p.v2,
                           n, (rem >> 1)*4, (rem & 1)*16, t);
        }
    } else {
        int t = s - 2;
        if (t >= 0 && t < 10) {
            int idx = bid - 384;
            int n = idx >> 2, rem = idx & 3;
            l23_step<3,16>(smem, p, p.hs3, p.pl2, p.pl3, p.cst3,
                           p.U3b, p.W3b, p.bp + 256,
                           p.g3, p.be3, p.m3, p.v3,
                           n, rem*4, 0, t);
        }
    }
}

// ---------------- dense layer 1: K-split partial GEMM ----------------
__global__ __launch_bounds__(256)
void dense1(const unsigned short* __restrict__ flat, const float* __restrict__ Wd1,
            float* __restrict__ partial)
{
    __shared__ __align__(16) float xs[256*8];   // [kk][r]
    const int kc = blockIdx.x, k0 = kc*256;
    const int t = threadIdx.x;
    {
        int r = t >> 5, kb = (t & 31)*8;
        short8 v = *(const short8*)(flat + (long)r*20480 + k0 + kb);
        #pragma unroll
        for (int e = 0; e < 8; ++e) xs[(kb+e)*8 + r] = bf2f((unsigned short)v[e]);
    }
    __syncthreads();
    const int c = t & 63, seg = t >> 6;
    f32x4 accA = {0,0,0,0}, accB = {0,0,0,0};
    #pragma unroll 4
    for (int kk = seg*64; kk < seg*64 + 64; ++kk) {
        float w = Wd1[(long)(k0+kk)*64 + c];
        f32x4 xa = *(const f32x4*)&xs[kk*8];
        f32x4 xb = *(const f32x4*)&xs[kk*8 + 4];
        #pragma unroll
        for (int j = 0; j < 4; ++j) { accA[j] = fmaf(xa[j], w, accA[j]); accB[j] = fmaf(xb[j], w, accB[j]); }
    }
    __syncthreads();
    #pragma unroll
    for (int j = 0; j < 4; ++j) {
        xs[(seg*8 + j)*64 + c]     = accA[j];
        xs[(seg*8 + 4 + j)*64 + c] = accB[j];
    }
    __syncthreads();
    #pragma unroll
    for (int o = t; o < 512; o += 256) {
        int r = o >> 6, cc = o & 63;
        partial[(long)kc*512 + o] = (xs[(0*8+r)*64+cc] + xs[(1*8+r)*64+cc])
                                  + (xs[(2*8+r)*64+cc] + xs[(3*8+r)*64+cc]);
    }
}

// ---------------- dense tail: reduce partials, softmax, 64x10, softmax ----------------
__global__ __launch_bounds__(512)
void dense_tail(const float* __restrict__ partial, const float* __restrict__ bd1,
                const float* __restrict__ Wd2, const float* __restrict__ bd2,
                float* __restrict__ outp)
{
    __shared__ float d1[512];
    __shared__ float l2s[80];
    const int t = threadIdx.x;
    const int c = t & 63;
    float s = bd1[c];
    #pragma unroll 4
    for (int kc = 0; kc < 80; ++kc) s += partial[kc*512 + t];
    float mx = s;
    for (int o = 32; o > 0; o >>= 1) mx = fmaxf(mx, __shfl_xor(mx, o, 64));
    float e = __expf(s - mx);
    float sm = e;
    for (int o = 32; o > 0; o >>= 1) sm += __shfl_xor(sm, o, 64);
    d1[t] = e / sm;
    __syncthreads();
    if (t < 80) {
        int r = t / 10, o = t % 10;
        float l = bd2[o];
        #pragma unroll 8
        for (int cc = 0; cc < 64; ++cc) l = fmaf(d1[r*64 + cc], Wd2[cc*10 + o], l);
        l2s[t] = l;
    }
    __syncthreads();
    if (t < 8) {
        float mx2 = l2s[t*10];
        #pragma unroll
        for (int j = 1; j < 10; ++j) mx2 = fmaxf(mx2, l2s[t*10 + j]);
        float ev[10], s2 = 0.f;
        #pragma unroll
        for (int j = 0; j < 10; ++j) { ev[j] = __expf(l2s[t*10 + j] - mx2); s2 += ev[j]; }
        #pragma unroll
        for (int j = 0; j < 10; ++j) outp[t*10 + j] = ev[j] / s2;
    }
}

extern "C" void kernel_launch(void* const* d_in, const int* in_sizes, int n_in,
                              void* d_out, int out_size, void* d_ws, size_t ws_size,
                              hipStream_t stream)
{
    const float* x   = (const float*)d_in[0];
    const float* W1  = (const float*)d_in[1];
    const float* U1  = (const float*)d_in[2];
    const float* b1  = (const float*)d_in[3];
    const float* Wd1 = (const float*)d_in[22];
    const float* bd1 = (const float*)d_in[23];
    const float* Wd2 = (const float*)d_in[24];
    const float* bd2 = (const float*)d_in[25];

    char* ws = (char*)d_ws;
    SP p;
    p.x   = x;
    p.g1  = (const float*)d_in[4];  p.be1 = (const float*)d_in[5];  p.m1 = (const float*)d_in[6];  p.v1 = (const float*)d_in[7];
    p.g2  = (const float*)d_in[11]; p.be2 = (const float*)d_in[12]; p.m2 = (const float*)d_in[13]; p.v2 = (const float*)d_in[14];
    p.g3  = (const float*)d_in[18]; p.be3 = (const float*)d_in[19]; p.m3 = (const float*)d_in[20]; p.v3 = (const float*)d_in[21];

    p.hs1 = (unsigned short*)(ws);                  // 20,971,520
    p.hs2 = (unsigned short*)(ws + 20971520);       //  5,242,880
    p.hs3 = (unsigned short*)(ws + 26214400);       //  1,310,720
    p.cst1 = (float*)(ws + 27525120);               //  4,194,304
    p.cst2 = (float*)(ws + 31719424);               //  1,048,576
    p.cst3 = (float*)(ws + 32768000);               //    262,144
    p.pl1 = (unsigned short*)(ws + 33030144);       //  5,242,880
    p.pl2 = (unsigned short*)(ws + 38273024);       //  1,310,720
    p.pl3 = (unsigned short*)(ws + 39583744);       //    327,680
    short8* U1b = (short8*)(ws + 39911424);         //    204,800
    short8* W1b = (short8*)(ws + 40116224);         //     24,576
    short8* U2b = (short8*)(ws + 40140800);         //    204,800
    short8* W2b = (short8*)(ws + 40345600);         //    204,800
    short8* U3b = (short8*)(ws + 40550400);         //     73,728
    short8* W3b = (short8*)(ws + 40624128);         //     73,728
    float*  bp  = (float*)(ws + 40697856);          //      1,536
    float*  partial = (float*)(ws + 40699392);      //    163,840
    p.U1b = U1b; p.W1b = W1b; p.U2b = U2b; p.W2b = W2b; p.U3b = U3b; p.W3b = W3b;
    p.bp = bp;

    xform_all<<<194, 256, 0, stream>>>(U1, W1,
        (const float*)d_in[9], (const float*)d_in[8],
        (const float*)d_in[16], (const float*)d_in[15],
        b1, (const float*)d_in[10], (const float*)d_in[17],
        U1b, W1b, U2b, W2b, U3b, W3b, bp);

    for (int s = 0; s < 12; ++s)
        stage_k<<<416, 256, 0, stream>>>(p, s);

    dense1<<<80, 256, 0, stream>>>(p.pl3, Wd1, partial);
    dense_tail<<<1, 512, 0, stream>>>(partial, bd1, Wd2, bd2, (float*)d_out);
}